// Round 1
// baseline (448.019 us; speedup 1.0000x reference)
//
#include <hip/hip_runtime.h>

// Butterfly multiply, B=16384, N=2048, LOG_N=11, increasing stride.
// Element layout: e = r*128 + lane*2 + j   (r in [0,16), j in {0,1})
// Register k = 2*r + j. Stage st (s=2^st), p = ((e>>(st+1))<<st) | (e & (s-1)),
// twiddle flat: st*4096 + 4*p + 2*i + jj.
//   stage 0      (s=1)        : pair = j bit, in-lane, global float4 twiddle
//   stages 1..6  (s=2..64)    : pair = lane bit (st-1) -> DPP / ds_swizzle / shfl
//   stages 7..10 (s=128..1024): pair = r bit (st-7), in-register
//
// R5 redesign (latency-bound fix): the old kernel re-loaded the full 176 KiB
// twiddle set from L2 per wave (~272 loads x ~200cyc, VALUBusy 31%, occ 20%).
// Now each 16 KiB per-stage table is DMA'd into double-buffered LDS with
// __builtin_amdgcn_global_load_lds while the previous stage computes; the
// __syncthreads() vmcnt-drain at stage end is the completion point.
//   - ROWS 2->4: halves per-row twiddle/shuffle work. 128 data VGPRs.
//   - LDS XOR swizzle (word bit5 -> bit2, 16B-block granularity): butterfly
//     read patterns are stride-8-words = 4-way bank conflict; swizzle makes
//     them ~2-way (free). global_load_lds writes linearly, so the swizzle is
//     applied by permuting the per-lane GLOBAL source (guide rule #21),
//     slot s holds global float4 s^((s>>3)&1) (involution).
//   - shuffles: masks 1,2 via DPP quad_perm (VALU pipe), 4,8,16 via
//     ds_swizzle (no index setup), 32 via __shfl_xor.
// CRITICAL (R4 lesson): every loop fully unrolled; all v[][] indices
// compile-time, else scratch allocation.

constexpr int BATCH = 16384;
constexpr int N = 2048;
constexpr int ROWS = 4;             // rows per wave
constexpr int WPB = 4;              // waves per block
constexpr int BLOCK = 64 * WPB;     // 256 threads
constexpr int GRID = BATCH / (ROWS * WPB);   // 1024 blocks

// Read-side LDS word-address swizzle: XOR bit5 into bit2 (16B granularity,
// preserves float2/float4 contiguity+alignment). Inverse of the staging
// permutation in float4-index space: f' = f ^ ((f>>3)&1).
__device__ __forceinline__ int swz(int a) { return a ^ (((a >> 5) & 1) << 2); }

// Cross-lane partner (lane ^ M), cheapest pipe per mask.
template <int M>
__device__ __forceinline__ float part_xor(float x) {
    if constexpr (M == 1)        // quad_perm [1,0,3,2]
        return __int_as_float(__builtin_amdgcn_mov_dpp(__float_as_int(x), 0xB1, 0xF, 0xF, true));
    else if constexpr (M == 2)   // quad_perm [2,3,0,1]
        return __int_as_float(__builtin_amdgcn_mov_dpp(__float_as_int(x), 0x4E, 0xF, 0xF, true));
    else if constexpr (M == 4)   // xor 4 within 32-half
        return __int_as_float(__builtin_amdgcn_ds_swizzle(__float_as_int(x), 0x101F));
    else if constexpr (M == 8)
        return __int_as_float(__builtin_amdgcn_ds_swizzle(__float_as_int(x), 0x201F));
    else if constexpr (M == 16)
        return __int_as_float(__builtin_amdgcn_ds_swizzle(__float_as_int(x), 0x401F));
    else
        return __shfl_xor(x, 32, 64);
}

// stages 1..6 (s=2..64): pair bit is a lane bit -> cross-lane partner
template <int ST>
__device__ __forceinline__ void mid_stage(float (&v)[ROWS][32], const float* twb, int lane) {
    constexpr int s = 1 << ST;
    constexpr int m = 1 << (ST - 1);
    const int hiHalf = (lane >> (ST - 1)) & 1;
    const int l2 = lane * 2;
    #pragma unroll
    for (int k = 0; k < 32; ++k) {
        const int e = (k >> 1) * 128 + l2 + (k & 1);
        const int p = ((e >> (ST + 1)) << ST) | (e & (s - 1));
        const int a = swz(4 * p + 2 * hiHalf);
        const float2 t2 = *(const float2*)(twb + a);
        #pragma unroll
        for (int rr = 0; rr < ROWS; ++rr) {
            const float mine = v[rr][k];
            const float part = part_xor<m>(mine);
            const float lo = hiHalf ? part : mine;
            const float hi = hiHalf ? mine : part;
            v[rr][k] = fmaf(t2.x, lo, t2.y * hi);
        }
    }
}

// stages 7..10 (s=128..1024): pair bit is an r bit -> in-register
template <int ST>
__device__ __forceinline__ void hi_stage(float (&v)[ROWS][32], const float* twb, int lane) {
    constexpr int s = 1 << ST;
    constexpr int rm = 1 << (ST - 7);
    const int l2 = lane * 2;
    #pragma unroll
    for (int r = 0; r < 16; ++r) {
        if (r & rm) continue;                  // visit each pair at lo (compile-time)
        #pragma unroll
        for (int j = 0; j < 2; ++j) {
            const int e = r * 128 + l2 + j;
            const int p = ((e >> (ST + 1)) << ST) | (e & (s - 1));
            const int a = swz(4 * p);
            const float4 t4 = *(const float4*)(twb + a);
            const int klo = 2 * r + j;
            const int khi = 2 * (r + rm) + j;
            #pragma unroll
            for (int rr = 0; rr < ROWS; ++rr) {
                const float lo = v[rr][klo];
                const float hi = v[rr][khi];
                v[rr][klo] = fmaf(t4.x, lo, t4.y * hi);
                v[rr][khi] = fmaf(t4.z, lo, t4.w * hi);
            }
        }
    }
}

__global__ __launch_bounds__(BLOCK, 3)
void butterfly_kernel(const float* __restrict__ x,
                      const float* __restrict__ tw,
                      const float* __restrict__ bias,
                      float* __restrict__ out)
{
    __shared__ __align__(16) float lds[2][4096];   // 2 x 16 KiB stage tables
    const int tid = threadIdx.x;
    const int lane = tid & 63;
    const int w = tid >> 6;
    const int wid = blockIdx.x * WPB + w;
    const size_t row0 = (size_t)wid * ROWS;
    const int l2 = lane * 2;

    // DMA stage st's 16 KiB table into lds[buf]. LDS dest is wave-uniform
    // (HW adds lane*16); global src is per-lane and carries the swizzle:
    // linear LDS slot s receives global float4 s^((s>>3)&1).
    auto stage_tw = [&](int st, int buf) {
        const float* base = tw + (st << 12);
        #pragma unroll
        for (int i = 0; i < 4; ++i) {
            const int s = i * 256 + (w << 6) + lane;        // linear float4 slot
            const int g = s ^ ((s >> 3) & 1);               // swizzled source
            __builtin_amdgcn_global_load_lds(
                (const __attribute__((address_space(1))) void*)(base + 4 * g),
                (__attribute__((address_space(3))) void*)(&lds[buf][(i * 256 + (w << 6)) * 4]),
                16, 0, 0);
        }
    };

    stage_tw(1, 1);     // prefetch stage-1 table under x-load + stage 0

    float v[ROWS][32];

    // ---- coalesced float2 x loads (512 B per wave-inst)
    #pragma unroll
    for (int rr = 0; rr < ROWS; ++rr) {
        const float* src = x + (row0 + rr) * N + l2;
        #pragma unroll
        for (int r = 0; r < 16; ++r) {
            const float2 f = *(const float2*)(src + r * 128);
            v[rr][2*r]   = f.x;
            v[rr][2*r+1] = f.y;
        }
    }

    // ---- stage 0 (s=1): in-lane pair, twiddle straight from global
    // (perfectly coalesced float4, L2-resident; stays off the LDS pipeline)
    #pragma unroll
    for (int r = 0; r < 16; ++r) {
        const float4 t4 = *(const float4*)(tw + 4 * (r * 64 + lane));
        #pragma unroll
        for (int rr = 0; rr < ROWS; ++rr) {
            const float lo = v[rr][2*r];
            const float hi = v[rr][2*r+1];
            v[rr][2*r]   = fmaf(t4.x, lo, t4.y * hi);
            v[rr][2*r+1] = fmaf(t4.z, lo, t4.w * hi);
        }
    }
    __syncthreads();    // vmcnt drain: stage-1 table landed for all waves

    // Steady state: prefetch st+1 into the idle buffer (its readers finished
    // at the previous barrier), compute st from the fresh buffer, barrier
    // (drains the prefetch + all ds_reads).
    stage_tw(2, 0);  mid_stage<1>(v, &lds[1][0], lane); __syncthreads();
    stage_tw(3, 1);  mid_stage<2>(v, &lds[0][0], lane); __syncthreads();
    stage_tw(4, 0);  mid_stage<3>(v, &lds[1][0], lane); __syncthreads();
    stage_tw(5, 1);  mid_stage<4>(v, &lds[0][0], lane); __syncthreads();
    stage_tw(6, 0);  mid_stage<5>(v, &lds[1][0], lane); __syncthreads();
    stage_tw(7, 1);  mid_stage<6>(v, &lds[0][0], lane); __syncthreads();
    stage_tw(8, 0);  hi_stage<7>(v, &lds[1][0], lane);  __syncthreads();
    stage_tw(9, 1);  hi_stage<8>(v, &lds[0][0], lane);  __syncthreads();
    stage_tw(10, 0); hi_stage<9>(v, &lds[1][0], lane);  __syncthreads();
    hi_stage<10>(v, &lds[0][0], lane);

    // ---- coalesced float2 stores with bias
    #pragma unroll
    for (int r = 0; r < 16; ++r) {
        const float2 b = *(const float2*)(bias + r * 128 + l2);
        #pragma unroll
        for (int rr = 0; rr < ROWS; ++rr) {
            float2 o;
            o.x = v[rr][2*r]   + b.x;
            o.y = v[rr][2*r+1] + b.y;
            *(float2*)(out + (row0 + rr) * N + r * 128 + l2) = o;
        }
    }
}

extern "C" void kernel_launch(void* const* d_in, const int* in_sizes, int n_in,
                              void* d_out, int out_size, void* d_ws, size_t ws_size,
                              hipStream_t stream) {
    const float* x    = (const float*)d_in[0];
    const float* tw   = (const float*)d_in[1];
    const float* bias = (const float*)d_in[2];
    float* out = (float*)d_out;

    butterfly_kernel<<<GRID, BLOCK, 0, stream>>>(x, tw, bias, out);
}